// Round 13
// baseline (383.950 us; speedup 1.0000x reference)
//
#include <hip/hip_runtime.h>

#define N_NODES 100000
#define F 64
#define C 32
#define KH 3
#define E 1600000
#define NE (KH * E)                        // 4,800,000 edges

#define NSLICE 4                           // y col-slices; 3.2 MB < 4 MB L2/XCD
#define SLICEW 25000
#define NKEY (N_NODES * NSLICE)            // 400,000 sort keys (row*4 + slice)
#define KPB 512                            // keys per coarse bucket (= 128 rows)
#define NBUCK ((NKEY + KPB - 1) / KPB)     // 782
#define HCHUNK 4096                        // edges per hist block
#define NHCHUNK ((NE + HCHUNK - 1) / HCHUNK)   // 1172
#define CHUNK1 8192                        // edges per part1 block
#define NCHUNK1 ((NE + CHUNK1 - 1) / CHUNK1)   // 586
#define P2CAP 8192                         // part2 LDS capacity (mean 6144, sd 78)
#define GEMM_BLOCKS ((N_NODES * 2 + 255) / 256) // 782

// ---------------------------------------------------------------------------
// K1: FUSED gemm + coarse histogram (disjoint block ranges). [proven r12]
// ---------------------------------------------------------------------------
__global__ __launch_bounds__(256) void gemm_hist_k(const float* __restrict__ x,
                                                   const float* __restrict__ W,
                                                   float* __restrict__ y,
                                                   const int* __restrict__ rows,
                                                   int* __restrict__ hcnt) {
    __shared__ float smem[F * C];  // 8 KB; reused as int hh[NBUCK] in hist role

    if (blockIdx.x < GEMM_BLOCKS) {
        float* Ws = smem;
        for (int i = threadIdx.x; i < F * C; i += 256) Ws[i] = W[i];
        __syncthreads();

        const int g = blockIdx.x * 256 + threadIdx.x;
        if (g >= N_NODES * 2) return;
        const int node = g >> 1;
        const int h = (g & 1) * 16;

        const float4* xp = (const float4*)(x + (size_t)node * F);
        float acc[16];
#pragma unroll
        for (int c = 0; c < 16; c++) acc[c] = 0.f;

#pragma unroll
        for (int i = 0; i < 16; i++) {
            float4 v = xp[i];
            const int f = i * 4;
#pragma unroll
            for (int c = 0; c < 16; c++) {
                acc[c] += v.x * Ws[(f + 0) * C + h + c];
                acc[c] += v.y * Ws[(f + 1) * C + h + c];
                acc[c] += v.z * Ws[(f + 2) * C + h + c];
                acc[c] += v.w * Ws[(f + 3) * C + h + c];
            }
        }

        float4* yo = (float4*)(y + (size_t)node * C + h);
#pragma unroll
        for (int i = 0; i < 4; i++)
            yo[i] = make_float4(acc[4 * i], acc[4 * i + 1], acc[4 * i + 2], acc[4 * i + 3]);
    } else {
        int* hh = (int*)smem;
        for (int i = threadIdx.x; i < NBUCK; i += 256) hh[i] = 0;
        __syncthreads();
        const int base = (blockIdx.x - GEMM_BLOCKS) * HCHUNK;
#pragma unroll
        for (int j = 0; j < 4; j++) {
            const int e = base + j * 1024 + threadIdx.x * 4;
            if (e + 3 < NE) {
                const int4 r4 = *(const int4*)(rows + e);
                atomicAdd(&hh[r4.x >> 7], 1);
                atomicAdd(&hh[r4.y >> 7], 1);
                atomicAdd(&hh[r4.z >> 7], 1);
                atomicAdd(&hh[r4.w >> 7], 1);
            }
        }
        __syncthreads();
        for (int i = threadIdx.x; i < NBUCK; i += 256) {
            const int cc = hh[i];
            if (cc) atomicAdd(&hcnt[i], cc);
        }
    }
}

// ---------------------------------------------------------------------------
// K3: single-block scan of 782 bucket counts -> bstart, bcur, rs sentinel.
// ---------------------------------------------------------------------------
__global__ __launch_bounds__(256) void scan_c(const int* __restrict__ hcnt,
                                              int* __restrict__ bstart,
                                              int* __restrict__ bcur,
                                              int* __restrict__ rs_start) {
    __shared__ int sA[1024], sB[1024];
    const int tid = threadIdx.x;
    for (int i = tid; i < 1024; i += 256) sA[i] = (i < NBUCK) ? hcnt[i] : 0;
    __syncthreads();
    int* src = sA;
    int* dst = sB;
    for (int d = 1; d < 1024; d <<= 1) {
        for (int i = tid; i < 1024; i += 256) {
            int v = src[i];
            if (i >= d) v += src[i - d];
            dst[i] = v;
        }
        __syncthreads();
        int* t = src; src = dst; dst = t;
    }
    for (int i = tid; i < NBUCK; i += 256) {
        const int excl = (i == 0) ? 0 : src[i - 1];
        bstart[i] = excl;
        bcur[i] = excl;
    }
    if (tid == 0) {
        bstart[NBUCK] = NE;
        rs_start[NKEY] = NE;
    }
}

// ---------------------------------------------------------------------------
// K4: part1 — LDS-staged coarse partition. 1024 threads: 16 waves/CU at the
// same 1 WG/CU (90 KB LDS) — double the latency hiding for the random flush.
// bucket = row>>7. Entry: { (key&511)<<17 | col , val*alpha }.
// ---------------------------------------------------------------------------
__global__ __launch_bounds__(1024) void part1_k(const float* __restrict__ vals,
                                                const int* __restrict__ rows,
                                                const int* __restrict__ cols,
                                                const float* __restrict__ alpha,
                                                int* __restrict__ bcur,
                                                int2* __restrict__ edgebuf) {
    __shared__ int sA[1024];                 // counts -> (in-place) inclusive scan
    __shared__ int wtot[16];
    __shared__ int lpos[NBUCK];
    __shared__ int lbase[NBUCK];
    __shared__ int2 stage[CHUNK1];           // 64 KB
    __shared__ unsigned short sbin[CHUNK1];  // 16 KB

    const int tid = threadIdx.x;
    const int base = blockIdx.x * CHUNK1;

    sA[tid] = 0;
    __syncthreads();

    int kj[8], cj[8];
    float wj[8];
#pragma unroll
    for (int j = 0; j < 2; j++) {
        const int e = base + j * 4096 + tid * 4;
        if (e + 3 < NE) {  // E, NE multiples of 4: group uniform hop, no straddle
            const int4   r4 = *(const int4*)(rows + e);
            const int4   c4 = *(const int4*)(cols + e);
            const float4 v4 = *(const float4*)(vals + e);
            const float ak = alpha[(e >= 2 * E) ? 2 : (e >= E) ? 1 : 0];
            kj[j * 4 + 0] = r4.x * NSLICE + c4.x / SLICEW; cj[j * 4 + 0] = c4.x; wj[j * 4 + 0] = v4.x * ak;
            kj[j * 4 + 1] = r4.y * NSLICE + c4.y / SLICEW; cj[j * 4 + 1] = c4.y; wj[j * 4 + 1] = v4.y * ak;
            kj[j * 4 + 2] = r4.z * NSLICE + c4.z / SLICEW; cj[j * 4 + 2] = c4.z; wj[j * 4 + 2] = v4.z * ak;
            kj[j * 4 + 3] = r4.w * NSLICE + c4.w / SLICEW; cj[j * 4 + 3] = c4.w; wj[j * 4 + 3] = v4.w * ak;
            atomicAdd(&sA[kj[j * 4 + 0] >> 9], 1);
            atomicAdd(&sA[kj[j * 4 + 1] >> 9], 1);
            atomicAdd(&sA[kj[j * 4 + 2] >> 9], 1);
            atomicAdd(&sA[kj[j * 4 + 3] >> 9], 1);
        } else {
            kj[j * 4 + 0] = kj[j * 4 + 1] = kj[j * 4 + 2] = kj[j * 4 + 3] = -1;
        }
    }
    __syncthreads();

    {   // wave-scan over 1024 bins, 1 bin/thread, in-place in sA
        const int lane = tid & 63;
        const int w = tid >> 6;
        const int a0 = sA[tid];
        int sc = a0;
#pragma unroll
        for (int d = 1; d < 64; d <<= 1) {
            int u = __shfl_up(sc, d);
            if (lane >= d) sc += u;
        }
        if (lane == 63) wtot[w] = sc;
        __syncthreads();   // all reads of sA done; wtot visible
        int wb = 0;
#pragma unroll
        for (int q = 0; q < 16; q++)
            if (q < w) wb += wtot[q];
        sA[tid] = wb + sc;  // inclusive scan
    }
    __syncthreads();

    if (tid < NBUCK) {
        const int excl = (tid == 0) ? 0 : sA[tid - 1];
        const int cnt = sA[tid] - excl;
        lpos[tid] = excl;
        if (cnt) lbase[tid] = atomicAdd(&bcur[tid], cnt);
    }
    __syncthreads();

#pragma unroll
    for (int j = 0; j < 8; j++) {
        if (kj[j] >= 0) {
            const int b = kj[j] >> 9;
            const int p = atomicAdd(&lpos[b], 1);
            stage[p] = make_int2(((kj[j] & (KPB - 1)) << 17) | cj[j],
                                 __float_as_int(wj[j]));
            sbin[p] = (unsigned short)b;
        }
    }
    __syncthreads();

    const int total = sA[1023];
    for (int p = tid; p < total; p += 1024) {
        const int b = sbin[p];
        const int excl = (b == 0) ? 0 : sA[b - 1];
        edgebuf[lbase[b] + (p - excl)] = stage[p];
    }
}

// ---------------------------------------------------------------------------
// K5: part2 — per-bucket in-LDS counting sort. 512 threads (proven r11/r12).
// ---------------------------------------------------------------------------
__global__ __launch_bounds__(512) void part2_k(const int* __restrict__ bstart,
                                               int* __restrict__ rs_start,
                                               int2* __restrict__ edgebuf) {
    __shared__ int2 sstage[P2CAP];   // 64 KB
    __shared__ int sh[KPB];          // counts
    __shared__ int sg[KPB];          // inclusive scan
    __shared__ int wtot[8];
    __shared__ int lbin[KPB];        // write cursors

    const int tid = threadIdx.x;
    const int b = blockIdx.x;
    const int bs = bstart[b];
    const int be = bstart[b + 1];
    const int n = be - bs;

    for (int k = tid; k < KPB; k += 512) sh[k] = 0;
    __syncthreads();

    if (n <= P2CAP) {
        for (int i = tid; i < n; i += 512) {
            const int2 e = edgebuf[bs + i];
            sstage[i] = e;
            atomicAdd(&sh[((unsigned)e.x) >> 17], 1);
        }
    }
    __syncthreads();

    {   // wave-scan: 512 threads, 1 sub-key each
        const int lane = tid & 63;
        const int w = tid >> 6;
        const int a0 = sh[tid];
        int sc = a0;
#pragma unroll
        for (int d = 1; d < 64; d <<= 1) {
            int u = __shfl_up(sc, d);
            if (lane >= d) sc += u;
        }
        if (lane == 63) wtot[w] = sc;
        __syncthreads();
        int wb = 0;
#pragma unroll
        for (int q = 0; q < 8; q++)
            if (q < w) wb += wtot[q];
        sg[tid] = wb + sc;
    }
    __syncthreads();

    for (int k = tid; k < KPB; k += 512) {
        const int st = bs + ((k == 0) ? 0 : sg[k - 1]);
        lbin[k] = st;
        const int idx = (b << 9) + k;
        if (idx < NKEY) rs_start[idx] = st;
    }
    __syncthreads();

    if (n > P2CAP) return;  // 26-sigma impossible

    for (int i = tid; i < n; i += 512) {
        const int2 e = sstage[i];
        const int sub = ((unsigned)e.x) >> 17;
        const int pos = atomicAdd(&lbin[sub], 1);
        edgebuf[pos] = e;
    }
}

// ---------------------------------------------------------------------------
// K6: gather — half-wave (32 lanes = channels) per (row, slice) task, 8 tasks
// per block. BROADCAST structure: lane c loads eb[i+c] (one coalesced 256B
// load = up to 32 edges), then per edge j: __shfl broadcast + y gather.
// A whole n<=32 task = 2 dependent memory rounds (eb round, then n
// independent y loads) — no serialized scalar tail.
// ---------------------------------------------------------------------------
__global__ __launch_bounds__(256) void gatherb_k(const long long* __restrict__ eb,
                                                 const int* __restrict__ rs_start,
                                                 const float* __restrict__ y,
                                                 const float* __restrict__ bias,
                                                 float* __restrict__ out) {
    const int blk = blockIdx.x;
    const int s = blk & (NSLICE - 1);
    const int row = (blk >> 2) * 8 + (threadIdx.x >> 5);
    const int c = threadIdx.x & 31;
    const int key = row * NSLICE + s;
    const int st = rs_start[key];
    const int en = rs_start[key + 1];

    float acc = (s == 0) ? bias[c] : 0.f;

    for (int i = st; i < en; i += 32) {
        const int m = min(32, en - i);
        long long my = 0;
        if (c < m) my = __builtin_nontemporal_load(&eb[i + c]);
#pragma unroll 4
        for (int j = 0; j < m; j++) {
            const long long e = __shfl(my, j, 32);  // within-half-wave broadcast
            acc += __int_as_float((int)(e >> 32)) * y[(((int)e) & 0x1FFFF) * C + c];
        }
    }

    unsafeAtomicAdd(out + (size_t)row * C + c, acc);
}

// ---------------------------------------------------------------------------
// Fallback (proven): atomic scatter if workspace too small.
// ---------------------------------------------------------------------------
__global__ __launch_bounds__(256) void scatter_edges(
    const float* __restrict__ vals, const int* __restrict__ rows,
    const int* __restrict__ cols, const float* __restrict__ alpha,
    const float* __restrict__ y, float* __restrict__ out_acc) {
    const int t = blockIdx.x * 256 + threadIdx.x;
    const int e = t >> 5;
    const int c = t & 31;
    if (e >= KH * E) return;
    const int k = (e >= 2 * E) ? 2 : (e >= E) ? 1 : 0;
    const float w = vals[e] * alpha[k];
    const float yv = y[(size_t)cols[e] * C + c];
    unsafeAtomicAdd(out_acc + (size_t)rows[e] * C + c, w * yv);
}

__global__ __launch_bounds__(256) void gemm_only_k(const float* __restrict__ x,
                                                   const float* __restrict__ W,
                                                   float* __restrict__ y) {
    __shared__ float Ws[F * C];
    for (int i = threadIdx.x; i < F * C; i += 256) Ws[i] = W[i];
    __syncthreads();
    const int g = blockIdx.x * 256 + threadIdx.x;
    if (g >= N_NODES * 2) return;
    const int node = g >> 1;
    const int h = (g & 1) * 16;
    const float4* xp = (const float4*)(x + (size_t)node * F);
    float acc[16];
#pragma unroll
    for (int c = 0; c < 16; c++) acc[c] = 0.f;
#pragma unroll
    for (int i = 0; i < 16; i++) {
        float4 v = xp[i];
        const int f = i * 4;
#pragma unroll
        for (int c = 0; c < 16; c++) {
            acc[c] += v.x * Ws[(f + 0) * C + h + c];
            acc[c] += v.y * Ws[(f + 1) * C + h + c];
            acc[c] += v.z * Ws[(f + 2) * C + h + c];
            acc[c] += v.w * Ws[(f + 3) * C + h + c];
        }
    }
    float4* yo = (float4*)(y + (size_t)node * C + h);
#pragma unroll
    for (int i = 0; i < 4; i++)
        yo[i] = make_float4(acc[4 * i], acc[4 * i + 1], acc[4 * i + 2], acc[4 * i + 3]);
}

__global__ __launch_bounds__(256) void finalize_k(float* __restrict__ out,
                                                  const float* __restrict__ bias) {
    const int idx = (blockIdx.x * 256 + threadIdx.x) * 4;
    if (idx >= N_NODES * C) return;
    const int c0 = idx & (C - 1);
    float4 v = *(float4*)(out + idx);
    v.x += bias[c0 + 0];
    v.y += bias[c0 + 1];
    v.z += bias[c0 + 2];
    v.w += bias[c0 + 3];
    *(float4*)(out + idx) = v;
}

// ---------------------------------------------------------------------------
extern "C" void kernel_launch(void* const* d_in, const int* in_sizes, int n_in,
                              void* d_out, int out_size, void* d_ws, size_t ws_size,
                              hipStream_t stream) {
    const float* x         = (const float*)d_in[0];
    const float* edge_vals = (const float*)d_in[1];
    const float* W         = (const float*)d_in[2];
    const float* b         = (const float*)d_in[3];
    const float* alpha     = (const float*)d_in[4];
    const int*   edge_rows = (const int*)d_in[5];
    const int*   edge_cols = (const int*)d_in[6];
    float*       out       = (float*)d_out;

    // Workspace layout (proven to fit: ~52.81 MB)
    const size_t offY   = 0;                                   // 12,800,000
    const size_t offEB  = (size_t)N_NODES * C * 4;             // +38,400,000
    const size_t offRS  = offEB + (size_t)NE * 8;              // 51,200,000
    const size_t offBS  = offRS + (((size_t)(NKEY + 1) * 4 + 255) & ~(size_t)255);
    const size_t offBC  = offBS + (((NBUCK + 1) * 4 + 255) & ~(size_t)255);
    const size_t offHC  = offBC + ((NBUCK * 4 + 255) & ~(size_t)255);
    const size_t need   = offHC + (size_t)NBUCK * 4;

    float* y = (float*)((char*)d_ws + offY);

    if (ws_size >= need) {
        int2* edgebuf  = (int2*)((char*)d_ws + offEB);
        int*  rs_start = (int*)((char*)d_ws + offRS);
        int*  bstart   = (int*)((char*)d_ws + offBS);
        int*  bcur     = (int*)((char*)d_ws + offBC);
        int*  hcnt     = (int*)((char*)d_ws + offHC);

        hipMemsetAsync(hcnt, 0, (size_t)NBUCK * 4, stream);
        hipMemsetAsync(out, 0, (size_t)N_NODES * C * sizeof(float), stream);

        gemm_hist_k<<<GEMM_BLOCKS + NHCHUNK, 256, 0, stream>>>(
            x, W, y, edge_rows, hcnt);
        scan_c<<<1, 256, 0, stream>>>(hcnt, bstart, bcur, rs_start);
        part1_k<<<NCHUNK1, 1024, 0, stream>>>(edge_vals, edge_rows, edge_cols,
                                              alpha, bcur, edgebuf);
        part2_k<<<NBUCK, 512, 0, stream>>>(bstart, rs_start, edgebuf);
        gatherb_k<<<(N_NODES / 8) * NSLICE, 256, 0, stream>>>(
            (const long long*)edgebuf, rs_start, y, b, out);
    } else {
        gemm_only_k<<<GEMM_BLOCKS, 256, 0, stream>>>(x, W, y);
        hipMemsetAsync(out, 0, (size_t)N_NODES * C * sizeof(float), stream);
        const long long scatter_threads = (long long)KH * E * C;
        const int scatter_blocks = (int)((scatter_threads + 255) / 256);
        scatter_edges<<<scatter_blocks, 256, 0, stream>>>(
            edge_vals, edge_rows, edge_cols, alpha, y, out);
        finalize_k<<<(N_NODES * C / 4 + 255) / 256, 256, 0, stream>>>(out, b);
    }
}

// Round 14
// 343.133 us; speedup vs baseline: 1.1190x; 1.1190x over previous
//
#include <hip/hip_runtime.h>

#define N_NODES 100000
#define F 64
#define C 32
#define KH 3
#define E 1600000
#define NE (KH * E)                        // 4,800,000 edges

#define NSLICE 4                           // y col-slices; 3.2 MB < 4 MB L2/XCD
#define SLICEW 25000
#define NKEY (N_NODES * NSLICE)            // 400,000 sort keys (row*4 + slice)
#define KPB 512                            // keys per coarse bucket (= 128 rows)
#define NBUCK ((NKEY + KPB - 1) / KPB)     // 782
#define HCHUNK 4096                        // edges per hist block
#define NHCHUNK ((NE + HCHUNK - 1) / HCHUNK)   // 1172
#define CHUNK1 8192                        // edges per part1 block
#define NCHUNK1 ((NE + CHUNK1 - 1) / CHUNK1)   // 586
#define P2CAP 8192                         // part2 LDS capacity (mean 6144, sd 78)
#define GEMM_BLOCKS ((N_NODES * 2 + 255) / 256) // 782

// ---------------------------------------------------------------------------
// K1: FUSED gemm + coarse histogram (disjoint block ranges). [proven r12/r13]
// ---------------------------------------------------------------------------
__global__ __launch_bounds__(256) void gemm_hist_k(const float* __restrict__ x,
                                                   const float* __restrict__ W,
                                                   float* __restrict__ y,
                                                   const int* __restrict__ rows,
                                                   int* __restrict__ hcnt) {
    __shared__ float smem[F * C];  // 8 KB; reused as int hh[NBUCK] in hist role

    if (blockIdx.x < GEMM_BLOCKS) {
        float* Ws = smem;
        for (int i = threadIdx.x; i < F * C; i += 256) Ws[i] = W[i];
        __syncthreads();

        const int g = blockIdx.x * 256 + threadIdx.x;
        if (g >= N_NODES * 2) return;
        const int node = g >> 1;
        const int h = (g & 1) * 16;

        const float4* xp = (const float4*)(x + (size_t)node * F);
        float acc[16];
#pragma unroll
        for (int c = 0; c < 16; c++) acc[c] = 0.f;

#pragma unroll
        for (int i = 0; i < 16; i++) {
            float4 v = xp[i];
            const int f = i * 4;
#pragma unroll
            for (int c = 0; c < 16; c++) {
                acc[c] += v.x * Ws[(f + 0) * C + h + c];
                acc[c] += v.y * Ws[(f + 1) * C + h + c];
                acc[c] += v.z * Ws[(f + 2) * C + h + c];
                acc[c] += v.w * Ws[(f + 3) * C + h + c];
            }
        }

        float4* yo = (float4*)(y + (size_t)node * C + h);
#pragma unroll
        for (int i = 0; i < 4; i++)
            yo[i] = make_float4(acc[4 * i], acc[4 * i + 1], acc[4 * i + 2], acc[4 * i + 3]);
    } else {
        int* hh = (int*)smem;
        for (int i = threadIdx.x; i < NBUCK; i += 256) hh[i] = 0;
        __syncthreads();
        const int base = (blockIdx.x - GEMM_BLOCKS) * HCHUNK;
#pragma unroll
        for (int j = 0; j < 4; j++) {
            const int e = base + j * 1024 + threadIdx.x * 4;
            if (e + 3 < NE) {
                const int4 r4 = *(const int4*)(rows + e);
                atomicAdd(&hh[r4.x >> 7], 1);
                atomicAdd(&hh[r4.y >> 7], 1);
                atomicAdd(&hh[r4.z >> 7], 1);
                atomicAdd(&hh[r4.w >> 7], 1);
            }
        }
        __syncthreads();
        for (int i = threadIdx.x; i < NBUCK; i += 256) {
            const int cc = hh[i];
            if (cc) atomicAdd(&hcnt[i], cc);
        }
    }
}

// ---------------------------------------------------------------------------
// K3: single-block scan of 782 bucket counts -> bstart, bcur, rs sentinel.
// ---------------------------------------------------------------------------
__global__ __launch_bounds__(256) void scan_c(const int* __restrict__ hcnt,
                                              int* __restrict__ bstart,
                                              int* __restrict__ bcur,
                                              int* __restrict__ rs_start) {
    __shared__ int sA[1024], sB[1024];
    const int tid = threadIdx.x;
    for (int i = tid; i < 1024; i += 256) sA[i] = (i < NBUCK) ? hcnt[i] : 0;
    __syncthreads();
    int* src = sA;
    int* dst = sB;
    for (int d = 1; d < 1024; d <<= 1) {
        for (int i = tid; i < 1024; i += 256) {
            int v = src[i];
            if (i >= d) v += src[i - d];
            dst[i] = v;
        }
        __syncthreads();
        int* t = src; src = dst; dst = t;
    }
    for (int i = tid; i < NBUCK; i += 256) {
        const int excl = (i == 0) ? 0 : src[i - 1];
        bstart[i] = excl;
        bcur[i] = excl;
    }
    if (tid == 0) {
        bstart[NBUCK] = NE;
        rs_start[NKEY] = NE;
    }
}

// ---------------------------------------------------------------------------
// K4: part1 — LDS-staged coarse partition. 1024 threads (proven r13).
// bucket = row>>7. Entry: { (key&511)<<17 | col , val*alpha }.
// ---------------------------------------------------------------------------
__global__ __launch_bounds__(1024) void part1_k(const float* __restrict__ vals,
                                                const int* __restrict__ rows,
                                                const int* __restrict__ cols,
                                                const float* __restrict__ alpha,
                                                int* __restrict__ bcur,
                                                int2* __restrict__ edgebuf) {
    __shared__ int sA[1024];                 // counts -> (in-place) inclusive scan
    __shared__ int wtot[16];
    __shared__ int lpos[NBUCK];
    __shared__ int lbase[NBUCK];
    __shared__ int2 stage[CHUNK1];           // 64 KB
    __shared__ unsigned short sbin[CHUNK1];  // 16 KB

    const int tid = threadIdx.x;
    const int base = blockIdx.x * CHUNK1;

    sA[tid] = 0;
    __syncthreads();

    int kj[8], cj[8];
    float wj[8];
#pragma unroll
    for (int j = 0; j < 2; j++) {
        const int e = base + j * 4096 + tid * 4;
        if (e + 3 < NE) {  // E, NE multiples of 4: group uniform hop, no straddle
            const int4   r4 = *(const int4*)(rows + e);
            const int4   c4 = *(const int4*)(cols + e);
            const float4 v4 = *(const float4*)(vals + e);
            const float ak = alpha[(e >= 2 * E) ? 2 : (e >= E) ? 1 : 0];
            kj[j * 4 + 0] = r4.x * NSLICE + c4.x / SLICEW; cj[j * 4 + 0] = c4.x; wj[j * 4 + 0] = v4.x * ak;
            kj[j * 4 + 1] = r4.y * NSLICE + c4.y / SLICEW; cj[j * 4 + 1] = c4.y; wj[j * 4 + 1] = v4.y * ak;
            kj[j * 4 + 2] = r4.z * NSLICE + c4.z / SLICEW; cj[j * 4 + 2] = c4.z; wj[j * 4 + 2] = v4.z * ak;
            kj[j * 4 + 3] = r4.w * NSLICE + c4.w / SLICEW; cj[j * 4 + 3] = c4.w; wj[j * 4 + 3] = v4.w * ak;
            atomicAdd(&sA[kj[j * 4 + 0] >> 9], 1);
            atomicAdd(&sA[kj[j * 4 + 1] >> 9], 1);
            atomicAdd(&sA[kj[j * 4 + 2] >> 9], 1);
            atomicAdd(&sA[kj[j * 4 + 3] >> 9], 1);
        } else {
            kj[j * 4 + 0] = kj[j * 4 + 1] = kj[j * 4 + 2] = kj[j * 4 + 3] = -1;
        }
    }
    __syncthreads();

    {   // wave-scan over 1024 bins, 1 bin/thread, in-place in sA
        const int lane = tid & 63;
        const int w = tid >> 6;
        const int a0 = sA[tid];
        int sc = a0;
#pragma unroll
        for (int d = 1; d < 64; d <<= 1) {
            int u = __shfl_up(sc, d);
            if (lane >= d) sc += u;
        }
        if (lane == 63) wtot[w] = sc;
        __syncthreads();   // all reads of sA done; wtot visible
        int wb = 0;
#pragma unroll
        for (int q = 0; q < 16; q++)
            if (q < w) wb += wtot[q];
        sA[tid] = wb + sc;  // inclusive scan
    }
    __syncthreads();

    if (tid < NBUCK) {
        const int excl = (tid == 0) ? 0 : sA[tid - 1];
        const int cnt = sA[tid] - excl;
        lpos[tid] = excl;
        if (cnt) lbase[tid] = atomicAdd(&bcur[tid], cnt);
    }
    __syncthreads();

#pragma unroll
    for (int j = 0; j < 8; j++) {
        if (kj[j] >= 0) {
            const int b = kj[j] >> 9;
            const int p = atomicAdd(&lpos[b], 1);
            stage[p] = make_int2(((kj[j] & (KPB - 1)) << 17) | cj[j],
                                 __float_as_int(wj[j]));
            sbin[p] = (unsigned short)b;
        }
    }
    __syncthreads();

    const int total = sA[1023];
    for (int p = tid; p < total; p += 1024) {
        const int b = sbin[p];
        const int excl = (b == 0) ? 0 : sA[b - 1];
        edgebuf[lbase[b] + (p - excl)] = stage[p];
    }
}

// ---------------------------------------------------------------------------
// K5: part2 — per-bucket in-LDS counting sort. 512 threads (proven r11-r13).
// ---------------------------------------------------------------------------
__global__ __launch_bounds__(512) void part2_k(const int* __restrict__ bstart,
                                               int* __restrict__ rs_start,
                                               int2* __restrict__ edgebuf) {
    __shared__ int2 sstage[P2CAP];   // 64 KB
    __shared__ int sh[KPB];          // counts
    __shared__ int sg[KPB];          // inclusive scan
    __shared__ int wtot[8];
    __shared__ int lbin[KPB];        // write cursors

    const int tid = threadIdx.x;
    const int b = blockIdx.x;
    const int bs = bstart[b];
    const int be = bstart[b + 1];
    const int n = be - bs;

    for (int k = tid; k < KPB; k += 512) sh[k] = 0;
    __syncthreads();

    if (n <= P2CAP) {
        for (int i = tid; i < n; i += 512) {
            const int2 e = edgebuf[bs + i];
            sstage[i] = e;
            atomicAdd(&sh[((unsigned)e.x) >> 17], 1);
        }
    }
    __syncthreads();

    {   // wave-scan: 512 threads, 1 sub-key each
        const int lane = tid & 63;
        const int w = tid >> 6;
        const int a0 = sh[tid];
        int sc = a0;
#pragma unroll
        for (int d = 1; d < 64; d <<= 1) {
            int u = __shfl_up(sc, d);
            if (lane >= d) sc += u;
        }
        if (lane == 63) wtot[w] = sc;
        __syncthreads();
        int wb = 0;
#pragma unroll
        for (int q = 0; q < 8; q++)
            if (q < w) wb += wtot[q];
        sg[tid] = wb + sc;
    }
    __syncthreads();

    for (int k = tid; k < KPB; k += 512) {
        const int st = bs + ((k == 0) ? 0 : sg[k - 1]);
        lbin[k] = st;
        const int idx = (b << 9) + k;
        if (idx < NKEY) rs_start[idx] = st;
    }
    __syncthreads();

    if (n > P2CAP) return;  // 26-sigma impossible

    for (int i = tid; i < n; i += 512) {
        const int2 e = sstage[i];
        const int sub = ((unsigned)e.x) >> 17;
        const int pos = atomicAdd(&lbin[sub], 1);
        edgebuf[pos] = e;
    }
}

// ---------------------------------------------------------------------------
// K6: gather — half-wave per (row, slice) task, 8 tasks/block. BROADCAST
// structure with COMPILE-TIME 32-iter fully-unrolled body (fixes r13's
// runtime-bound partial unroll): lane c loads eb[i+c] (coalesced 256B);
// lanes >= m hold my=0 -> col 0, weight 0.0 (adds exactly 0; the garbage
// loads all hit one hot line y[0..31]). All 32 shfls + 32 y-loads are
// independent and hoistable: a whole n<=32 task = 2 dependent memory rounds.
// ---------------------------------------------------------------------------
__global__ __launch_bounds__(256) void gatherb2_k(const long long* __restrict__ eb,
                                                  const int* __restrict__ rs_start,
                                                  const float* __restrict__ y,
                                                  const float* __restrict__ bias,
                                                  float* __restrict__ out) {
    const int blk = blockIdx.x;
    const int s = blk & (NSLICE - 1);
    const int row = (blk >> 2) * 8 + (threadIdx.x >> 5);
    const int c = threadIdx.x & 31;
    const int key = row * NSLICE + s;
    const int st = rs_start[key];
    const int en = rs_start[key + 1];

    float acc = (s == 0) ? bias[c] : 0.f;

    for (int i = st; i < en; i += 32) {
        const int m = en - i;   // > 0 inside loop
        long long my = 0;       // col=0, w=+0.0f for lanes >= m
        if (c < m) my = __builtin_nontemporal_load(&eb[i + c]);
#pragma unroll
        for (int j = 0; j < 32; j++) {
            const long long e = __shfl(my, j, 32);  // within-half-wave broadcast
            acc += __int_as_float((int)(e >> 32)) * y[(((int)e) & 0x1FFFF) * C + c];
        }
    }

    unsafeAtomicAdd(out + (size_t)row * C + c, acc);
}

// ---------------------------------------------------------------------------
// Fallback (proven): atomic scatter if workspace too small.
// ---------------------------------------------------------------------------
__global__ __launch_bounds__(256) void scatter_edges(
    const float* __restrict__ vals, const int* __restrict__ rows,
    const int* __restrict__ cols, const float* __restrict__ alpha,
    const float* __restrict__ y, float* __restrict__ out_acc) {
    const int t = blockIdx.x * 256 + threadIdx.x;
    const int e = t >> 5;
    const int c = t & 31;
    if (e >= KH * E) return;
    const int k = (e >= 2 * E) ? 2 : (e >= E) ? 1 : 0;
    const float w = vals[e] * alpha[k];
    const float yv = y[(size_t)cols[e] * C + c];
    unsafeAtomicAdd(out_acc + (size_t)rows[e] * C + c, w * yv);
}

__global__ __launch_bounds__(256) void gemm_only_k(const float* __restrict__ x,
                                                   const float* __restrict__ W,
                                                   float* __restrict__ y) {
    __shared__ float Ws[F * C];
    for (int i = threadIdx.x; i < F * C; i += 256) Ws[i] = W[i];
    __syncthreads();
    const int g = blockIdx.x * 256 + threadIdx.x;
    if (g >= N_NODES * 2) return;
    const int node = g >> 1;
    const int h = (g & 1) * 16;
    const float4* xp = (const float4*)(x + (size_t)node * F);
    float acc[16];
#pragma unroll
    for (int c = 0; c < 16; c++) acc[c] = 0.f;
#pragma unroll
    for (int i = 0; i < 16; i++) {
        float4 v = xp[i];
        const int f = i * 4;
#pragma unroll
        for (int c = 0; c < 16; c++) {
            acc[c] += v.x * Ws[(f + 0) * C + h + c];
            acc[c] += v.y * Ws[(f + 1) * C + h + c];
            acc[c] += v.z * Ws[(f + 2) * C + h + c];
            acc[c] += v.w * Ws[(f + 3) * C + h + c];
        }
    }
    float4* yo = (float4*)(y + (size_t)node * C + h);
#pragma unroll
    for (int i = 0; i < 4; i++)
        yo[i] = make_float4(acc[4 * i], acc[4 * i + 1], acc[4 * i + 2], acc[4 * i + 3]);
}

__global__ __launch_bounds__(256) void finalize_k(float* __restrict__ out,
                                                  const float* __restrict__ bias) {
    const int idx = (blockIdx.x * 256 + threadIdx.x) * 4;
    if (idx >= N_NODES * C) return;
    const int c0 = idx & (C - 1);
    float4 v = *(float4*)(out + idx);
    v.x += bias[c0 + 0];
    v.y += bias[c0 + 1];
    v.z += bias[c0 + 2];
    v.w += bias[c0 + 3];
    *(float4*)(out + idx) = v;
}

// ---------------------------------------------------------------------------
extern "C" void kernel_launch(void* const* d_in, const int* in_sizes, int n_in,
                              void* d_out, int out_size, void* d_ws, size_t ws_size,
                              hipStream_t stream) {
    const float* x         = (const float*)d_in[0];
    const float* edge_vals = (const float*)d_in[1];
    const float* W         = (const float*)d_in[2];
    const float* b         = (const float*)d_in[3];
    const float* alpha     = (const float*)d_in[4];
    const int*   edge_rows = (const int*)d_in[5];
    const int*   edge_cols = (const int*)d_in[6];
    float*       out       = (float*)d_out;

    // Workspace layout (proven to fit: ~52.81 MB)
    const size_t offY   = 0;                                   // 12,800,000
    const size_t offEB  = (size_t)N_NODES * C * 4;             // +38,400,000
    const size_t offRS  = offEB + (size_t)NE * 8;              // 51,200,000
    const size_t offBS  = offRS + (((size_t)(NKEY + 1) * 4 + 255) & ~(size_t)255);
    const size_t offBC  = offBS + (((NBUCK + 1) * 4 + 255) & ~(size_t)255);
    const size_t offHC  = offBC + ((NBUCK * 4 + 255) & ~(size_t)255);
    const size_t need   = offHC + (size_t)NBUCK * 4;

    float* y = (float*)((char*)d_ws + offY);

    if (ws_size >= need) {
        int2* edgebuf  = (int2*)((char*)d_ws + offEB);
        int*  rs_start = (int*)((char*)d_ws + offRS);
        int*  bstart   = (int*)((char*)d_ws + offBS);
        int*  bcur     = (int*)((char*)d_ws + offBC);
        int*  hcnt     = (int*)((char*)d_ws + offHC);

        hipMemsetAsync(hcnt, 0, (size_t)NBUCK * 4, stream);
        hipMemsetAsync(out, 0, (size_t)N_NODES * C * sizeof(float), stream);

        gemm_hist_k<<<GEMM_BLOCKS + NHCHUNK, 256, 0, stream>>>(
            x, W, y, edge_rows, hcnt);
        scan_c<<<1, 256, 0, stream>>>(hcnt, bstart, bcur, rs_start);
        part1_k<<<NCHUNK1, 1024, 0, stream>>>(edge_vals, edge_rows, edge_cols,
                                              alpha, bcur, edgebuf);
        part2_k<<<NBUCK, 512, 0, stream>>>(bstart, rs_start, edgebuf);
        gatherb2_k<<<(N_NODES / 8) * NSLICE, 256, 0, stream>>>(
            (const long long*)edgebuf, rs_start, y, b, out);
    } else {
        gemm_only_k<<<GEMM_BLOCKS, 256, 0, stream>>>(x, W, y);
        hipMemsetAsync(out, 0, (size_t)N_NODES * C * sizeof(float), stream);
        const long long scatter_threads = (long long)KH * E * C;
        const int scatter_blocks = (int)((scatter_threads + 255) / 256);
        scatter_edges<<<scatter_blocks, 256, 0, stream>>>(
            edge_vals, edge_rows, edge_cols, alpha, y, out);
        finalize_k<<<(N_NODES * C / 4 + 255) / 256, 256, 0, stream>>>(out, b);
    }
}